// Round 6
// baseline (270.191 us; speedup 1.0000x reference)
//
#include <hip/hip_runtime.h>
#include <math.h>

#define DIN 640
#define DH 1024
#define DOUT 128
#define CODEDIM 256
#define NE 8
#define NB 8
#define NT 1024
#define TAU_INV 10.0f
#define FEPS 1e-8f

// out layout: full_output[8*1024*1024], aux[1], div[1], ent[8], mean[8], std[8]
#define AUX_OFF  8388608
#define DIV_OFF  8388609
#define ENT_OFF  8388610
#define MEAN_OFF 8388618
#define STD_OFF  8388626

// LDS geometry for k_main
#define XS_STRIDE 1288               // 640*2+8; %128==8 -> conflict-free b128 (r3: 0 conflicts)
#define HS_STRIDE 520                // 256*2+8 (pair = 256 H-cols)
#define BOFF 82944                   // A region [0, 64*1288=82432), rounded to 256
#define BUFSZ 16384                  // one B chunk tile: 128 rows x 128 B
#define LDS_TOTAL (BOFF + 4*BUFSZ)   // 148480 <= 160K -> 1 block/CU

typedef __bf16 bf16;
typedef bf16 bf16x4 __attribute__((ext_vector_type(4)));
typedef bf16 bf16x8 __attribute__((ext_vector_type(8)));
typedef float f32x16 __attribute__((ext_vector_type(16)));

#define BAR() do { asm volatile("" ::: "memory"); __builtin_amdgcn_s_barrier(); asm volatile("" ::: "memory"); } while(0)
#define VMCNT4 asm volatile("s_waitcnt vmcnt(4)" ::: "memory")
#define VMCNT0 asm volatile("s_waitcnt vmcnt(0)" ::: "memory")
#define LGKM0  asm volatile("s_waitcnt lgkmcnt(0)" ::: "memory")

// async global->LDS, 16B/lane; LDS dest is wave-uniform base (HW adds lane*16)
__device__ __forceinline__ void gload16(const void* g, void* l) {
  __builtin_amdgcn_global_load_lds(
      (const __attribute__((address_space(1))) unsigned int*)g,
      (__attribute__((address_space(3))) unsigned int*)l, 16, 0, 0);
}

// ---------------- block reduction helpers (blockDim multiple of 64) ----------
__device__ __forceinline__ float blk_sum(float v, float* sb) {
  #pragma unroll
  for (int o = 32; o > 0; o >>= 1) v += __shfl_down(v, o, 64);
  __syncthreads();
  if ((threadIdx.x & 63) == 0) sb[threadIdx.x >> 6] = v;
  __syncthreads();
  float tot = 0.f;
  int nw = blockDim.x >> 6;
  for (int i = 0; i < nw; ++i) tot += sb[i];
  return tot;
}

__device__ __forceinline__ float blk_max(float v, float* sb) {
  #pragma unroll
  for (int o = 32; o > 0; o >>= 1) v = fmaxf(v, __shfl_down(v, o, 64));
  __syncthreads();
  if ((threadIdx.x & 63) == 0) sb[threadIdx.x >> 6] = v;
  __syncthreads();
  float m = -3.0e38f;
  int nw = blockDim.x >> 6;
  for (int i = 0; i < nw; ++i) m = fmaxf(m, sb[i]);
  return m;
}

// ---------------- importance softmax + entropy/mean/std ---------------------
__global__ void k_imp(const float* __restrict__ fi, float* __restrict__ imp,
                      float* __restrict__ out) {
  __shared__ float sb[8];
  int e = blockIdx.x, tid = threadIdx.x;
  int d2v = tid + 512;
  float v0 = fi[e*DIN + tid] * 2.0f;          // /temp, temp = 0.5
  float v1 = fi[e*DIN + tid + 256] * 2.0f;
  float v2 = (d2v < DIN) ? fi[e*DIN + d2v] * 2.0f : -3.0e38f;
  float m = blk_max(fmaxf(v0, fmaxf(v1, v2)), sb);
  float e0 = expf(v0 - m), e1 = expf(v1 - m);
  float e2 = (d2v < DIN) ? expf(v2 - m) : 0.f;
  float s = blk_sum(e0 + e1 + e2, sb);
  float inv = 1.0f / s;
  float p0 = e0*inv, p1 = e1*inv, p2 = e2*inv;
  imp[e*DIN + tid] = p0;
  imp[e*DIN + tid + 256] = p1;
  if (d2v < DIN) imp[e*DIN + d2v] = p2;
  float ok2 = (d2v < DIN) ? 1.f : 0.f;
  float sp  = p0 + p1 + ok2*p2;
  float sp2 = p0*p0 + p1*p1 + ok2*p2*p2;
  float se  = p0*logf(p0 + FEPS) + p1*logf(p1 + FEPS) + ok2*p2*logf(p2 + FEPS);
  sp  = blk_sum(sp, sb);
  sp2 = blk_sum(sp2, sb);
  se  = blk_sum(se, sb);
  if (tid == 0) {
    out[ENT_OFF + e]  = -se;
    out[MEAN_OFF + e] = sp * (1.0f/DIN);
    float var = (sp2 - sp*sp*(1.0f/DIN)) * (1.0f/(DIN-1));
    out[STD_OFF + e]  = sqrtf(fmaxf(var, 0.f));
  }
}

// ---------------- anchor normalize + diversity loss --------------------------
__global__ void k_anchor_div(const float* __restrict__ ca, const float* __restrict__ fi,
                             float* __restrict__ anch, float* __restrict__ out) {
  __shared__ float sb[8];
  __shared__ float sd[256];
  int tid = threadIdx.x;
  for (int e = 0; e < NE; ++e) {
    float x = ca[e*CODEDIM + tid];
    float ss = blk_sum(x*x, sb);
    anch[e*CODEDIM + tid] = x / fmaxf(sqrtf(ss), 1e-12f);
  }
  // diversity: sim = fi @ fi^T, off-diag squared sum / 56
  int p = tid >> 2, q = tid & 3;     // pair p in 0..63, quarter q
  int i = p >> 3, j = p & 7;
  float dot = 0.f;
  for (int d = q*160; d < q*160 + 160; ++d) dot += fi[i*DIN + d] * fi[j*DIN + d];
  sd[tid] = dot;
  __syncthreads();
  if (tid < 64) {
    float s = sd[tid*4] + sd[tid*4+1] + sd[tid*4+2] + sd[tid*4+3];
    int ii = tid >> 3, jj = tid & 7;
    float val = (ii != jj) ? s*s : 0.f;
    #pragma unroll
    for (int o = 32; o > 0; o >>= 1) val += __shfl_down(val, o, 64);
    if (tid == 0) out[DIV_OFF] = val * (1.0f/56.0f);
  }
}

// -------- tiled transpose + f32->bf16 (+optional per-src-row scale) ----------
// src[e][R][C] -> dst[e][C][R]; dst[e][c][r] = src[e][r][c] * scale[e][r]
__global__ void k_transpose(const float* __restrict__ src, bf16* __restrict__ dst,
                            int R, int C, const float* __restrict__ scale) {
  __shared__ float tile[64][65];
  int c0 = blockIdx.x*64, r0 = blockIdx.y*64;
  int ee = blockIdx.z;
  const float* s = src + (size_t)ee*R*C;
  bf16* d = dst + (size_t)ee*C*R;
  int tx = threadIdx.x & 63, ty = threadIdx.x >> 6;
  #pragma unroll
  for (int p = 0; p < 16; ++p) {
    int r = p*4 + ty;
    tile[r][tx] = s[(size_t)(r0 + r)*C + c0 + tx];
  }
  __syncthreads();
  float sc = scale ? scale[(size_t)ee*R + r0 + tx] : 1.0f;
  #pragma unroll
  for (int p = 0; p < 16; ++p) {
    int cr = p*4 + ty;
    d[(size_t)(c0 + cr)*R + r0 + tx] = (bf16)(tile[tx][cr] * sc);
  }
}

// ---------------- h f32 -> bf16 (row-major, shared across experts) -----------
__global__ void k_h2b(const float* __restrict__ h, bf16* __restrict__ xb) {
  size_t i = (size_t)blockIdx.x*256 + threadIdx.x;   // 8 elements per thread
  const float4* p = (const float4*)(h + i*8);
  float4 v0 = p[0], v1 = p[1];
  bf16x8 o;
  o[0]=(bf16)v0.x; o[1]=(bf16)v0.y; o[2]=(bf16)v0.z; o[3]=(bf16)v0.w;
  o[4]=(bf16)v1.x; o[5]=(bf16)v1.y; o[6]=(bf16)v1.z; o[7]=(bf16)v1.w;
  *(bf16x8*)(xb + i*8) = o;
}

// ---------------- router: cosine logits + gumbel softmax ---------------------
__global__ void k_router(const float* __restrict__ ce, const float* __restrict__ gn,
                         const float* __restrict__ anch, float* __restrict__ ew) {
  __shared__ float anc[NE*CODEDIM];
  int tid = threadIdx.x;
  for (int i2 = tid; i2 < NE*CODEDIM; i2 += 256) anc[i2] = anch[i2];
  __syncthreads();
  int wv = tid >> 6, lane = tid & 63;
  int token = blockIdx.x*4 + wv;
  float4 x = *(const float4*)(ce + (size_t)token*CODEDIM + lane*4);
  float ss = x.x*x.x + x.y*x.y + x.z*x.z + x.w*x.w;
  #pragma unroll
  for (int o = 1; o < 64; o <<= 1) ss += __shfl_xor(ss, o, 64);
  float inv = 1.0f / fmaxf(sqrtf(ss), 1e-12f);
  const float* g = gn + (size_t)token*NE;
  float z[8];
  float m = -3.0e38f;
  #pragma unroll
  for (int e2 = 0; e2 < NE; ++e2) {
    const float* a = anc + e2*CODEDIM + lane*4;
    float d = x.x*a[0] + x.y*a[1] + x.z*a[2] + x.w*a[3];
    #pragma unroll
    for (int o = 1; o < 64; o <<= 1) d += __shfl_xor(d, o, 64);
    z[e2] = (d*inv + g[e2]) * TAU_INV;
    m = fmaxf(m, z[e2]);
  }
  float ssum = 0.f;
  float pz[8];
  #pragma unroll
  for (int e2 = 0; e2 < NE; ++e2) { pz[e2] = expf(z[e2] - m); ssum += pz[e2]; }
  float num = 0.f;
  #pragma unroll
  for (int e2 = 0; e2 < NE; ++e2) num = (lane == e2) ? pz[e2] : num;  // static idx
  if (lane < NE) ew[(size_t)token*NE + lane] = num / ssum;
}

// ---------------- fused MoE MLP ----------------------------------------------
// block = (expert e=bid&7 [XCD-pinned], 64-token M-tile). A (X-tile) resident
// in LDS once, padded stride (zero-conflict, r3-proven) -> kills the 8x A
// re-read (r5's 336MB FETCH). DH-chunks processed in PAIRS: one A-frag feeds
// 2 MFMAs (1.5KB LDS/MFMA) and barriers amortize 2x. B via global_load_lds,
// double-buffered, 3-bit XOR swizzle (r5-proven), counted vmcnt(4).
// Hs (pair, 33KB) ALIASES the B buffers (dead during epilogue/GEMM2):
// LDS total 148KB -> 1 block/CU; launch_bounds(512,2) -> 256 VGPR cap.
__global__ __launch_bounds__(512, 2)
void k_main(const bf16* __restrict__ xb, const bf16* __restrict__ w1t,
            const bf16* __restrict__ w2t,
            const float* __restrict__ b1, const float* __restrict__ b2,
            const float* __restrict__ ew, float* __restrict__ out) {
  __shared__ __align__(16) char L[LDS_TOTAL];
  const int bid = blockIdx.x;
  const int e = bid & 7;
  const int M0 = (bid >> 3) * 64;
  const int tid = threadIdx.x;
  const int lane = tid & 63, w = tid >> 6;
  const int l31 = lane & 31, hh = lane >> 5;
  const int rh = w >> 2, c4 = w & 3;           // 2 row-groups x 4 col-tiles
  const char* xby = (const char*)xb;
  const char* w1y = (const char*)w1t;

  // ---- A prologue: stage X-tile (64 x 640 bf16) resident, padded stride ----
  {
    const char* src = xby + (size_t)M0 * (DIN*2);
    #pragma unroll
    for (int j = 0; j < 10; ++j) {
      int fc = tid + 512*j;                    // 5120 chunks of 16B
      int row = fc / 80, cc = fc - row*80;
      bf16x8 v = *(const bf16x8*)(src + (size_t)row*(DIN*2) + cc*16);
      *(bf16x8*)(L + row*XS_STRIDE + cc*16) = v;
    }
  }

  // B staging: pair chunks (c=0,1); wave w stages rows 16w..16w+16 of each.
  // Inverse-swizzled global source + linear LDS dest (T21 both-sides rule).
  auto STAGE = [&](int buf, int pair, int t) {
    #pragma unroll
    for (int c = 0; c < 2; ++c) {
      #pragma unroll
      for (int j = 0; j < 2; ++j) {
        unsigned p = (unsigned)(w*2048 + j*1024 + lane*16);
        unsigned q = p ^ ((p >> 3) & 0x70u);
        const char* g = w1y + (size_t)(e*DH + (pair*2 + c)*128 + (int)(q >> 7))*(DIN*2)
                        + (q & 127) + t*128;
        gload16(g, L + BOFF + buf*32768 + c*16384 + w*2048 + j*1024);
      }
    }
  };

  const unsigned swz = (unsigned)((l31 & 7) << 4);
  const unsigned aB = (unsigned)((32*c4 + l31)*128 + hh*16);
  const unsigned aArow = (unsigned)((32*rh + l31)*XS_STRIDE + hh*16);
  f32x16 acc2 = {};

  STAGE(0, 0, 0);
  LGKM0;                 // A ds_writes drained (wave-local) before barrier
  BAR();

  for (int pp = 0; pp < 4; ++pp) {
    f32x16 acc1a = {}, acc1b = {};
    for (int t = 0; t < 10; ++t) {
      if (t < 9) { STAGE((t+1) & 1, pp, t+1); VMCNT4; }
      else       { VMCNT0; }
      BAR();
      const char* B0 = L + BOFF + (t & 1)*32768;
      const char* B1 = B0 + 16384;
      const unsigned aA = aArow + (unsigned)(t*128);
      #pragma unroll
      for (int ks = 0; ks < 4; ++ks) {
        bf16x8 af  = *(const bf16x8*)(L + aA + 32u*ks);
        bf16x8 bf0 = *(const bf16x8*)(B0 + ((aB + 32u*ks) ^ swz));
        bf16x8 bf1 = *(const bf16x8*)(B1 + ((aB + 32u*ks) ^ swz));
        acc1a = __builtin_amdgcn_mfma_f32_32x32x16_bf16(af, bf0, acc1a, 0, 0, 0);
        acc1b = __builtin_amdgcn_mfma_f32_32x32x16_bf16(af, bf1, acc1b, 0, 0, 0);
      }
      BAR();
    }
    // epilogue: +b1, exact GELU, bf16 -> Hs (aliases B bufs; sweep fully done)
    float bba = b1[e*DH + (pp*2 + 0)*128 + 32*c4 + l31];
    float bbb = b1[e*DH + (pp*2 + 1)*128 + 32*c4 + l31];
    int colb = (32*c4 + l31)*2;
    #pragma unroll
    for (int r = 0; r < 16; ++r) {
      int crow = (r & 3) + 8*(r >> 2) + 4*hh;
      char* hrow = L + BOFF + (32*rh + crow)*HS_STRIDE;
      float xa = acc1a[r] + bba;
      float xv = acc1b[r] + bbb;
      *(bf16*)(hrow + colb)       = (bf16)(0.5f*xa*(1.0f + erff(xa*0.70710678118654752f)));
      *(bf16*)(hrow + 256 + colb) = (bf16)(0.5f*xv*(1.0f + erff(xv*0.70710678118654752f)));
    }
    LGKM0;
    BAR();
    // GEMM2 partial over this pair's 256 H-cols (B2 frags from L2-resident W2)
    const bf16* pB2 = w2t + (size_t)(e*DOUT + 32*c4 + l31)*DH + pp*256 + 8*hh;
    const unsigned aH = (unsigned)((32*rh + l31)*HS_STRIDE + hh*16);
    #pragma unroll
    for (int kk = 0; kk < 16; ++kk) {
      bf16x8 a2  = *(const bf16x8*)(L + BOFF + aH + 32u*kk);
      bf16x8 b2f = *(const bf16x8*)(pB2 + 16*kk);
      acc2 = __builtin_amdgcn_mfma_f32_32x32x16_bf16(a2, b2f, acc2, 0, 0, 0);
    }
    BAR();                               // Hs reads done before restage hits bufs
    if (pp < 3) STAGE(0, pp + 1, 0);
  }
  // output: +b2, *gate, f32 store
  float bb2 = b2[e*DOUT + 32*c4 + l31];
  #pragma unroll
  for (int r = 0; r < 16; ++r) {
    int crow = (r & 3) + 8*(r >> 2) + 4*hh;
    int m = M0 + 32*rh + crow;
    float gate = ew[(size_t)m*NE + e];
    out[(size_t)m*(NE*DOUT) + e*DOUT + 32*c4 + l31] = (acc2[r] + bb2) * gate;
  }
}

// ---------------- expert counts + partial sums --------------------------------
__global__ void k_counts(const float* __restrict__ ew, float* __restrict__ counts,
                         float* __restrict__ partials) {
  __shared__ float sb[4];
  int g2 = blockIdx.x*256 + threadIdx.x;   // (t,e) flat, 0..8191
  float c = 0.f;
  #pragma unroll
  for (int b = 0; b < NB; ++b) c += ew[b*(NT*NE) + g2];
  counts[g2] = c;
  float tot = blk_sum(c, sb);
  if (threadIdx.x == 0) partials[blockIdx.x] = tot;
}

// ---------------- aux loss ----------------------------------------------------
__global__ void k_aux(const float* __restrict__ counts, const float* __restrict__ partials,
                      float* __restrict__ out) {
  __shared__ float sb[4];
  int tid = threadIdx.x;
  float pv = (tid < 32) ? partials[tid] : 0.f;
  float total = blk_sum(pv, sb);
  float invt = 1.0f / (total + FEPS);
  float sq = 0.f, ent = 0.f;
  for (int i2 = tid; i2 < NT*NE; i2 += 256) {
    float c = counts[i2];
    sq += c*c;
    float ld = c * invt;
    ent -= ld * logf(ld + FEPS);
  }
  sq = blk_sum(sq, sb);
  ent = blk_sum(ent, sb);
  if (tid == 0) {
    float var = (sq - total*total*(1.0f/(NT*NE))) * (1.0f/(NT*NE - 1));
    float stdv = sqrtf(fmaxf(var, 0.f));
    float ment = 0.f;
    #pragma unroll
    for (int e2 = 0; e2 < NE; ++e2) ment += out[ENT_OFF + e2];
    ment *= (1.0f/NE);
    out[AUX_OFF] = 0.5f*(stdv + ent) + 0.01f*ment;
  }
}

// ---------------- launch ------------------------------------------------------
extern "C" void kernel_launch(void* const* d_in, const int* in_sizes, int n_in,
                              void* d_out, int out_size, void* d_ws, size_t ws_size,
                              hipStream_t stream) {
  const float* h  = (const float*)d_in[0];
  const float* ce = (const float*)d_in[1];
  const float* gn = (const float*)d_in[2];
  const float* ca = (const float*)d_in[3];
  const float* fi = (const float*)d_in[4];
  const float* W1 = (const float*)d_in[5];
  const float* b1 = (const float*)d_in[6];
  const float* W2 = (const float*)d_in[7];
  const float* b2 = (const float*)d_in[8];
  float* out = (float*)d_out;
  char* ws = (char*)d_ws;
  // ws layout (bytes)
  bf16*  w1t      = (bf16*)(ws);                 // [E][DH][DIN] bf16 (imp-folded): 10,485,760
  bf16*  w2t      = (bf16*)(ws + 10485760);      // [E][DOUT][DH] bf16: 2,097,152
  bf16*  xbuf     = (bf16*)(ws + 12582912);      // [8192][640] bf16: 10,485,760
  float* imp      = (float*)(ws + 23068672);     // [E][DIN]: 20,480
  float* anch     = (float*)(ws + 23089152);     // [E][CODE]: 8,192
  float* ew       = (float*)(ws + 23097344);     // [B][T][E]: 262,144
  float* counts   = (float*)(ws + 23359488);     // [T*E]: 32,768
  float* partials = (float*)(ws + 23392256);     // [32]

  k_imp<<<dim3(8), dim3(256), 0, stream>>>(fi, imp, out);
  k_anchor_div<<<dim3(1), dim3(256), 0, stream>>>(ca, fi, anch, out);
  k_transpose<<<dim3(16, 10, 8), dim3(256), 0, stream>>>(W1, w1t, 640, 1024, imp);
  k_transpose<<<dim3(2, 16, 8), dim3(256), 0, stream>>>(W2, w2t, 1024, 128, nullptr);
  k_h2b<<<dim3(2560), dim3(256), 0, stream>>>(h, xbuf);
  k_router<<<dim3(2048), dim3(256), 0, stream>>>(ce, gn, anch, ew);
  k_main<<<dim3(1024), dim3(512), 0, stream>>>(xbuf, w1t, w2t, b1, b2, ew, out);
  k_counts<<<dim3(32), dim3(256), 0, stream>>>(ew, counts, partials);
  k_aux<<<dim3(1), dim3(256), 0, stream>>>(counts, partials, out);
}